// Round 1
// baseline (739.754 us; speedup 1.0000x reference)
//
#include <hip/hip_runtime.h>

#define NN 100000
#define MM 8
#define KK 256
#define DD 64

// Pre-kernel: csq[m*KK+k] = sum_d cb[m][k][d]^2  (2048 values into d_ws).
// Uniform-per-(m,k) quantity; computing it here keeps it out of the per-lane
// inner loop of the main kernel (would otherwise double the FMA count).
__global__ __launch_bounds__(256) void pq_csq_kernel(
    const float* __restrict__ cb, float* __restrict__ csq)
{
    int t = blockIdx.x * blockDim.x + threadIdx.x;
    if (t >= MM * KK) return;
    const float* c = cb + (size_t)t * DD;
    float s0 = 0.f, s1 = 0.f, s2 = 0.f, s3 = 0.f;
#pragma unroll
    for (int d = 0; d < DD; d += 4) {
        s0 = fmaf(c[d + 0], c[d + 0], s0);
        s1 = fmaf(c[d + 1], c[d + 1], s1);
        s2 = fmaf(c[d + 2], c[d + 2], s2);
        s3 = fmaf(c[d + 3], c[d + 3], s3);
    }
    csq[t] = (s0 + s1) + (s2 + s3);
}

// Main kernel: one thread per (n, m). m = blockIdx.y is wave-uniform so all
// codebook accesses have uniform addresses -> scalar loads (SMEM pipe),
// leaving the VALU free for the 256*64 fp32 FMAs per thread.
__global__ __launch_bounds__(256) void pq_main_kernel(
    const float* __restrict__ x, const float* __restrict__ cb,
    const float* __restrict__ csq, float* __restrict__ qout,
    float* __restrict__ idout)
{
    const int m = blockIdx.y;
    const int n = blockIdx.x * 256 + threadIdx.x;
    if (n >= NN) return;

    // Load this thread's 64-float subvector into VGPRs (float4 loads; each
    // thread consumes a contiguous 256B chunk -> no over-fetch).
    const float* xr = x + (size_t)n * (MM * DD) + m * DD;
    float xs[DD];
#pragma unroll
    for (int j = 0; j < DD / 4; ++j) {
        float4 v = reinterpret_cast<const float4*>(xr)[j];
        xs[4 * j + 0] = v.x; xs[4 * j + 1] = v.y;
        xs[4 * j + 2] = v.z; xs[4 * j + 3] = v.w;
    }

    // x_sq (per-thread, once)
    float q0 = 0.f, q1 = 0.f, q2 = 0.f, q3 = 0.f;
#pragma unroll
    for (int d = 0; d < DD; d += 4) {
        q0 = fmaf(xs[d + 0], xs[d + 0], q0);
        q1 = fmaf(xs[d + 1], xs[d + 1], q1);
        q2 = fmaf(xs[d + 2], xs[d + 2], q2);
        q3 = fmaf(xs[d + 3], xs[d + 3], q3);
    }
    const float xsq = (q0 + q1) + (q2 + q3);

    const float* cbm = cb + (size_t)m * KK * DD;
    const float* cqm = csq + m * KK;

    float best = 3.4028235e38f;
    int bestk = 0;
    // k unrolled x2, 2 partial accumulators each -> 4 independent FMA chains
    // (hides v_fma dep latency even at modest occupancy).
    for (int k = 0; k < KK; k += 2) {
        const float* c0 = cbm + (size_t)k * DD;
        const float* c1 = c0 + DD;
        float a0 = 0.f, a1 = 0.f, b0 = 0.f, b1 = 0.f;
#pragma unroll
        for (int d = 0; d < DD; d += 2) {
            a0 = fmaf(c0[d + 0], xs[d + 0], a0);
            a1 = fmaf(c0[d + 1], xs[d + 1], a1);
            b0 = fmaf(c1[d + 0], xs[d + 0], b0);
            b1 = fmaf(c1[d + 1], xs[d + 1], b1);
        }
        // mirror reference arithmetic: x_sq - 2*cross + c_sq (no fma here)
        const float dist0 = (xsq - 2.f * (a0 + a1)) + cqm[k];
        const float dist1 = (xsq - 2.f * (b0 + b1)) + cqm[k + 1];
        if (dist0 < best) { best = dist0; bestk = k; }       // strict < keeps
        if (dist1 < best) { best = dist1; bestk = k + 1; }   // first-min (np)
    }

    // Gather winning codeword -> Q_x
    const float4* cq = reinterpret_cast<const float4*>(cbm + (size_t)bestk * DD);
    float4* qo = reinterpret_cast<float4*>(qout + (size_t)n * (MM * DD) + m * DD);
#pragma unroll
    for (int j = 0; j < DD / 4; ++j) qo[j] = cq[j];

    // id_x is ids.T -> [m][n], stored as float into the float* d_out tail
    idout[(size_t)m * NN + n] = (float)bestk;
}

extern "C" void kernel_launch(void* const* d_in, const int* in_sizes, int n_in,
                              void* d_out, int out_size, void* d_ws, size_t ws_size,
                              hipStream_t stream)
{
    const float* x  = (const float*)d_in[0];
    const float* cb = (const float*)d_in[1];
    // d_in[2] = soft_rate = -1 (hard-assignment path only)

    float* qout  = (float*)d_out;
    float* idout = qout + (size_t)NN * (MM * DD);
    float* csq   = (float*)d_ws;   // 2048 floats

    pq_csq_kernel<<<dim3((MM * KK + 255) / 256), dim3(256), 0, stream>>>(cb, csq);

    dim3 grid((NN + 255) / 256, MM);
    pq_main_kernel<<<grid, dim3(256), 0, stream>>>(x, cb, csq, qout, idout);
}

// Round 3
// 442.128 us; speedup vs baseline: 1.6732x; 1.6732x over previous
//
#include <hip/hip_runtime.h>

#define NN 100000
#define MM 8
#define KK 256
#define DD 64
#define BROWS 128
#define NTILES ((NN + BROWS - 1) / BROWS)   // 782

typedef _Float16 half8 __attribute__((ext_vector_type(8)));
typedef float    f32x4 __attribute__((ext_vector_type(4)));

// ---------------------------------------------------------------------------
// ws layout (bytes):
//   [0,      256K)  cb_hi  half8[MM*8*256]   chunk-major: idx = m*2048 + c*256 + k
//   [256K,   512K)  cb_lo  (scaled x2048)
//   [512K,   520K)  csq    float[MM*KK]
// ---------------------------------------------------------------------------

__global__ __launch_bounds__(256) void pq_prep_kernel(
    const float* __restrict__ cb, half8* __restrict__ whi,
    half8* __restrict__ wlo, float* __restrict__ csq)
{
    const int t = blockIdx.x * 256 + threadIdx.x;      // 0..16383
    const int m = t >> 11, rest = t & 2047;
    const int c = rest >> 8, k = rest & 255;
    const float* src = cb + ((size_t)(m * KK + k)) * DD + c * 8;
    half8 h, l;
#pragma unroll
    for (int j = 0; j < 8; ++j) {
        float v = src[j];
        _Float16 hi = (_Float16)v;
        h[j] = hi;
        l[j] = (_Float16)((v - (float)hi) * 2048.0f);
    }
    whi[t] = h;
    wlo[t] = l;

    if (t < MM * KK) {
        const float* cr = cb + (size_t)t * DD;
        float s0 = 0.f, s1 = 0.f, s2 = 0.f, s3 = 0.f;
#pragma unroll
        for (int d = 0; d < DD; d += 4) {
            s0 = fmaf(cr[d + 0], cr[d + 0], s0);
            s1 = fmaf(cr[d + 1], cr[d + 1], s1);
            s2 = fmaf(cr[d + 2], cr[d + 2], s2);
            s3 = fmaf(cr[d + 3], cr[d + 3], s3);
        }
        csq[t] = (s0 + s1) + (s2 + s3);
    }
}

// Main: block = 128 rows x 1 m x 256 k. MFMA fp16-split distances for speed;
// rows whose top-2 MFMA distances are within DELTA get an exact fp32 rescore
// (identical arithmetic to the R1 kernel that matched numpy with absmax 0).
#define DELTA 4.0e-3f

__global__ __launch_bounds__(256, 2) void pq_main_kernel(
    const float* __restrict__ x, const half8* __restrict__ whi,
    const half8* __restrict__ wlo, const float* __restrict__ csqg,
    const float* __restrict__ cbf, float* __restrict__ qout,
    float* __restrict__ idout)
{
    __shared__ half8 Bh[8][128];    // 16 KB
    __shared__ half8 Bl[8][128];    // 16 KB
    __shared__ float csq_s[KK];     // 1 KB
    __shared__ int   cand_k[BROWS]; // 512 B

    const int m   = blockIdx.y;
    const int n0  = blockIdx.x * BROWS;
    const int tid = threadIdx.x;
    const int w = tid >> 6, L = tid & 63;
    const int q = L >> 4, ci = L & 15;

    csq_s[tid] = csqg[m * KK + tid];

    // A fragments: d = t*32 + q*8 + j on BOTH operands -> k-slot permutation
    // cancels (same mapping on A and B).
    half8 Ah[2][2], Al[2][2];
#pragma unroll
    for (int rb = 0; rb < 2; ++rb) {
        int n = n0 + w * 32 + rb * 16 + ci;
        if (n > NN - 1) n = NN - 1;                    // tail clamp (writes guarded)
        const float4* xp = (const float4*)(x + (size_t)n * (MM * DD) + m * DD);
#pragma unroll
        for (int t = 0; t < 2; ++t) {
            float4 v0 = xp[t * 8 + q * 2 + 0];
            float4 v1 = xp[t * 8 + q * 2 + 1];
            float vs[8] = {v0.x, v0.y, v0.z, v0.w, v1.x, v1.y, v1.z, v1.w};
#pragma unroll
            for (int j = 0; j < 8; ++j) {
                _Float16 hi = (_Float16)vs[j];
                Ah[rb][t][j] = hi;
                Al[rb][t][j] = (_Float16)((vs[j] - (float)hi) * 2048.0f);
            }
        }
    }

    // per-lane best (d1,k1) and second-best value d2, per output row slot
    float d1v[2][4], d2v[2][4];
    int   k1v[2][4];
#pragma unroll
    for (int rb = 0; rb < 2; ++rb)
#pragma unroll
        for (int r = 0; r < 4; ++r) { d1v[rb][r] = 3.4e38f; d2v[rb][r] = 3.4e38f; k1v[rb][r] = 0; }

    const half8* wh_m = whi + m * 2048;
    const half8* wl_m = wlo + m * 2048;

    for (int kh = 0; kh < 2; ++kh) {
        __syncthreads();
        for (int idx = tid; idx < 1024; idx += 256) {
            int c = idx >> 7, kl = idx & 127;
            Bh[c][kl] = wh_m[c * 256 + kh * 128 + kl];
            Bl[c][kl] = wl_m[c * 256 + kh * 128 + kl];
        }
        __syncthreads();

        for (int sc = 0; sc < 2; ++sc) {
            f32x4 acc1[2][4], acc2[2][4];
            const f32x4 z = {0.f, 0.f, 0.f, 0.f};
#pragma unroll
            for (int rb = 0; rb < 2; ++rb)
#pragma unroll
                for (int s = 0; s < 4; ++s) { acc1[rb][s] = z; acc2[rb][s] = z; }

#pragma unroll
            for (int sl = 0; sl < 4; ++sl) {
                const int kloc = (sc * 4 + sl) * 16 + ci;
                half8 bh0 = Bh[0 + q][kloc];
                half8 bh1 = Bh[4 + q][kloc];
                half8 bl0 = Bl[0 + q][kloc];
                half8 bl1 = Bl[4 + q][kloc];
#pragma unroll
                for (int rb = 0; rb < 2; ++rb) {
                    acc1[rb][sl] = __builtin_amdgcn_mfma_f32_16x16x32_f16(Ah[rb][0], bh0, acc1[rb][sl], 0, 0, 0);
                    acc1[rb][sl] = __builtin_amdgcn_mfma_f32_16x16x32_f16(Ah[rb][1], bh1, acc1[rb][sl], 0, 0, 0);
                    acc2[rb][sl] = __builtin_amdgcn_mfma_f32_16x16x32_f16(Ah[rb][0], bl0, acc2[rb][sl], 0, 0, 0);
                    acc2[rb][sl] = __builtin_amdgcn_mfma_f32_16x16x32_f16(Ah[rb][1], bl1, acc2[rb][sl], 0, 0, 0);
                    acc2[rb][sl] = __builtin_amdgcn_mfma_f32_16x16x32_f16(Al[rb][0], bh0, acc2[rb][sl], 0, 0, 0);
                    acc2[rb][sl] = __builtin_amdgcn_mfma_f32_16x16x32_f16(Al[rb][1], bh1, acc2[rb][sl], 0, 0, 0);
                }
            }
            // dist(sans xsq) = csq - 2*(acc1 + acc2/2048); C/D: col=lane&15, row=q*4+r
#pragma unroll
            for (int sl = 0; sl < 4; ++sl) {
                const int k = kh * 128 + (sc * 4 + sl) * 16 + ci;
                const float cq = csq_s[k];
#pragma unroll
                for (int rb = 0; rb < 2; ++rb)
#pragma unroll
                    for (int r = 0; r < 4; ++r) {
                        float cross = acc1[rb][sl][r] + acc2[rb][sl][r] * (1.0f / 2048.0f);
                        float d = cq - 2.0f * cross;
                        if (d < d1v[rb][r]) {
                            d2v[rb][r] = d1v[rb][r];
                            d1v[rb][r] = d; k1v[rb][r] = k;
                        } else if (d < d2v[rb][r]) {
                            d2v[rb][r] = d;
                        }
                    }
            }
        }
    }

    // Finalize each of the 8 row-slots: butterfly argmin; near-ties -> exact
    // fp32 rescore (R1 arithmetic, empirically bit-matching numpy's argmin).
#pragma unroll
    for (int rb = 0; rb < 2; ++rb)
#pragma unroll
        for (int r = 0; r < 4; ++r) {
            float d = d1v[rb][r];
            int   k = k1v[rb][r];
            for (int mask = 1; mask < 16; mask <<= 1) {
                float ds = __shfl_xor(d, mask);
                int   ks = __shfl_xor(k, mask);
                if (ds < d || (ds == d && ks < k)) { d = ds; k = ks; }
            }
            const float thr = d + DELTA;               // d == dmin, uniform
            int cnt = (d1v[rb][r] <= thr ? 1 : 0) + (d2v[rb][r] <= thr ? 1 : 0);
            for (int mask = 1; mask < 16; mask <<= 1) cnt += __shfl_xor(cnt, mask);

            const int n = n0 + w * 32 + rb * 16 + q * 4 + r;
            if (cnt > 1 && n < NN) {                   // rare exact path (q-group uniform)
                const float* xr = x + (size_t)n * (MM * DD) + m * DD;
                float s0 = 0.f, s1 = 0.f, s2 = 0.f, s3 = 0.f;
                for (int dd = 0; dd < DD; dd += 4) {
                    s0 = fmaf(xr[dd + 0], xr[dd + 0], s0);
                    s1 = fmaf(xr[dd + 1], xr[dd + 1], s1);
                    s2 = fmaf(xr[dd + 2], xr[dd + 2], s2);
                    s3 = fmaf(xr[dd + 3], xr[dd + 3], s3);
                }
                const float xsq = (s0 + s1) + (s2 + s3);
                float bd = 3.4e38f; int bk = 0;
                for (int j = 0; j < 16; ++j) {         // lane ci: k = ci + 16j (ascending)
                    const int kk = ci + 16 * j;
                    const float* c0 = cbf + ((size_t)(m * KK + kk)) * DD;
                    float a0 = 0.f, a1 = 0.f;
                    for (int dd = 0; dd < DD; dd += 2) {
                        a0 = fmaf(c0[dd + 0], xr[dd + 0], a0);
                        a1 = fmaf(c0[dd + 1], xr[dd + 1], a1);
                    }
                    const float dist = (xsq - 2.f * (a0 + a1)) + csq_s[kk];
                    if (dist < bd) { bd = dist; bk = kk; }   // strict <, ascending k
                }
                for (int mask = 1; mask < 16; mask <<= 1) {
                    float db = __shfl_xor(bd, mask);
                    int   kb = __shfl_xor(bk, mask);
                    if (db < bd || (db == bd && kb < bk)) { bd = db; bk = kb; }
                }
                k = bk;
            }
            if (ci == r) cand_k[w * 32 + rb * 16 + q * 4 + r] = k;
        }
    __syncthreads();

    if (tid < BROWS) {
        int n = n0 + tid;
        if (n < NN) idout[(size_t)m * NN + n] = (float)cand_k[tid];
    }
    for (int i = 0; i < 8; ++i) {
        int row = i * 16 + (tid >> 4);
        int n = n0 + row;
        if (n < NN) {
            int k = cand_k[row];
            int j = tid & 15;
            float4 v = ((const float4*)cbf)[(m * KK + k) * 16 + j];
            ((float4*)(qout + (size_t)n * (MM * DD) + m * DD))[j] = v;
        }
    }
}

extern "C" void kernel_launch(void* const* d_in, const int* in_sizes, int n_in,
                              void* d_out, int out_size, void* d_ws, size_t ws_size,
                              hipStream_t stream)
{
    const float* x  = (const float*)d_in[0];
    const float* cb = (const float*)d_in[1];

    float* qout  = (float*)d_out;
    float* idout = qout + (size_t)NN * (MM * DD);

    half8* whi = (half8*)d_ws;
    half8* wlo = (half8*)((char*)d_ws + 256 * 1024);
    float* csq = (float*)((char*)d_ws + 512 * 1024);

    pq_prep_kernel<<<dim3(64), dim3(256), 0, stream>>>(cb, whi, wlo, csq);

    pq_main_kernel<<<dim3(NTILES, MM), dim3(256), 0, stream>>>(
        x, whi, wlo, csq, cb, qout, idout);
}